// Round 12
// baseline (846.908 us; speedup 1.0000x reference)
//
#include <hip/hip_runtime.h>
#include <cstdint>
#include <cstddef>

#define NTOT 25600
#define BB 64
#define MAXN 512
#define DD 256
#define HH 8
#define FF 1024
#define HK 2048
#define NR (NTOT + BB)          // real rows + 1 pad-representative per batch
#define NK (BB * MAXN)          // 32768: vt column space (per-batch 512-aligned)
#define MT ((NR + 127) / 128)   // 201 M-tiles
#define QT 9                    // ceil((MAXN+1)/64) q-tiles
#define EPS 1e-3f
#define KST 260                 // k_lds row stride (2-way free)
#define VST 36                  // v_lds / p_lds row stride (reads conflict-free)
#define THR 8.0f                // defer-max rescale threshold (T13; zero-reg-cost)

typedef unsigned short u16;
typedef unsigned int   u32;
typedef __attribute__((ext_vector_type(8))) short s8v;   // 8 bf16 (4 VGPRs)
typedef __attribute__((ext_vector_type(4))) float f4v;   // MFMA accumulator

__device__ __forceinline__ float bf2f(u16 u) { return __uint_as_float(((u32)u) << 16); }
__device__ __forceinline__ u16 f2bf(float f) {
    u32 x = __float_as_uint(f);
    return (u16)((x + 0x7fffu + ((x >> 16) & 1u)) >> 16);  // RNE; inputs finite
}

// async global->LDS, 16B per lane. LDS dest must be wave-uniform base + lane*16.
typedef const __attribute__((address_space(1))) unsigned int gq_t;
typedef __attribute__((address_space(3))) unsigned int lq_t;
__device__ __forceinline__ void gld16(const void* g, void* l) {
    __builtin_amdgcn_global_load_lds((gq_t*)g, (lq_t*)(uintptr_t)l, 16, 0, 0);
}

// ---------------- K1: segment starts via binary search (indicator sorted) ----
__global__ void k_starts(const int* __restrict__ ind, int* __restrict__ starts) {
    int b = threadIdx.x;
    if (b > BB) return;
    int lo = 0, hi = NTOT;
    while (lo < hi) { int mid = (lo + hi) >> 1; if (ind[mid] < b) lo = mid + 1; else hi = mid; }
    starts[b] = lo;   // starts[64] == NTOT
}

// ---------------- K1b: row -> b*512 + local_pos map (-1 if beyond 512) -------
__global__ __launch_bounds__(256) void k_rowmap(const int* __restrict__ starts,
                                                int* __restrict__ rmap) {
    int row = blockIdx.x * 256 + threadIdx.x;
    if (row >= NTOT) return;
    int lo = 0, hi = BB - 1;
    while (lo < hi) { int mid = (lo + hi + 1) >> 1; if (starts[mid] <= row) lo = mid; else hi = mid - 1; }
    int m = row - starts[lo];
    rmap[row] = (m < MAXN) ? ((lo << 9) + m) : -1;
}

// ---------------- K2: x16 = bf16(x) (pad rows 0);  acc = x + bo --------------
__global__ __launch_bounds__(256) void k_cast_init(
    const float* __restrict__ x, const float* __restrict__ bo,
    u16* __restrict__ x16, float* __restrict__ acc) {
    int row = blockIdx.x, t = threadIdx.x;
    float v = (row < NTOT) ? x[(size_t)row * DD + t] : 0.f;
    x16[(size_t)row * DD + t] = f2bf(v);
    acc[(size_t)row * DD + t] = ((row < NTOT) ? v : 0.f) + bo[t];
}

// ---------------- K3: weight transposes via LDS 32x32 tile (coalesced) -------
__global__ __launch_bounds__(256) void k_prep_w(
    const float* __restrict__ Wq, const float* __restrict__ Wk, const float* __restrict__ Wv,
    const float* __restrict__ Wo, const float* __restrict__ W1, const float* __restrict__ W2,
    u16* __restrict__ WqT, u16* __restrict__ WkT, u16* __restrict__ WvT,
    u16* __restrict__ WoT, u16* __restrict__ W1T, u16* __restrict__ W2T)
{
    int bid = blockIdx.x;
    const float* W; u16* WT; int kd, nd;
    if (bid < 512)       { W = Wq; WT = WqT; kd = 256;  nd = 2048; }
    else if (bid < 1024) { W = Wk; WT = WkT; kd = 256;  nd = 2048; bid -= 512; }
    else if (bid < 1536) { W = Wv; WT = WvT; kd = 256;  nd = 2048; bid -= 1024; }
    else if (bid < 2048) { W = Wo; WT = WoT; kd = 2048; nd = 256;  bid -= 1536; }
    else if (bid < 2304) { W = W1; WT = W1T; kd = 256;  nd = 1024; bid -= 2048; }
    else                 { W = W2; WT = W2T; kd = 1024; nd = 256;  bid -= 2304; }
    int tn = nd >> 5;
    int k0 = (bid / tn) << 5, n0 = (bid % tn) << 5;
    __shared__ float tile[32][33];
    int t = threadIdx.x;
    int cr = t >> 5, cc = t & 31;
#pragma unroll
    for (int i = 0; i < 4; ++i)
        tile[cr + i * 8][cc] = W[(size_t)(k0 + cr + i * 8) * nd + n0 + cc];
    __syncthreads();
#pragma unroll
    for (int i = 0; i < 4; ++i)
        WT[(size_t)(n0 + cr + i * 8) * kd + k0 + cc] = f2bf(tile[cc][cr + i * 8]);
}

// ---------------- MFMA GEMM core: C[128x128]=A[128xkw]*BT^T, gload_lds stage -
__device__ __forceinline__ void gemm_core(
    const u16* __restrict__ A, int lda,
    const u16* __restrict__ BT, int ldb, int kbeg, int kw,
    int M, int m0, int n0, f4v acc[4][4])
{
    __shared__ u16 As[128 * 64];
    __shared__ u16 Bs[128 * 64];
    int t = threadIdx.x;
    int l = t & 63, w = t >> 6;
    int wm = (w >> 1) * 64, wn = (w & 1) * 64;
    const f4v z4 = {0.f, 0.f, 0.f, 0.f};
#pragma unroll
    for (int i = 0; i < 4; ++i)
#pragma unroll
        for (int j = 0; j < 4; ++j) acc[i][j] = z4;

    for (int k0 = 0; k0 < kw; k0 += 64) {
#pragma unroll
        for (int it = 0; it < 4; ++it) {
            int chunk = it * 256 + t;
            int r = chunk >> 3, c8 = (chunk & 7) * 8;
            int ga = m0 + r; ga = (ga < M) ? ga : (M - 1);   // clamp: no OOB fault
            gld16(&A[(size_t)ga * lda + k0 + c8], &As[chunk * 8]);
            gld16(&BT[(size_t)(n0 + r) * ldb + kbeg + k0 + c8], &Bs[chunk * 8]);
        }
        __syncthreads();   // barrier drains vmcnt -> LDS tiles complete
#pragma unroll
        for (int ks = 0; ks < 64; ks += 32) {
            s8v af[4], bf[4];
#pragma unroll
            for (int mt = 0; mt < 4; ++mt)
                af[mt] = *reinterpret_cast<const s8v*>(&As[(wm + mt * 16 + (l & 15)) * 64 + ks + (l >> 4) * 8]);
#pragma unroll
            for (int nt = 0; nt < 4; ++nt)
                bf[nt] = *reinterpret_cast<const s8v*>(&Bs[(wn + nt * 16 + (l & 15)) * 64 + ks + (l >> 4) * 8]);
#pragma unroll
            for (int mt = 0; mt < 4; ++mt)
#pragma unroll
                for (int nt = 0; nt < 4; ++nt)
                    acc[mt][nt] = __builtin_amdgcn_mfma_f32_16x16x32_bf16(af[mt], bf[nt], acc[mt][nt], 0, 0, 0);
        }
        __syncthreads();
    }
}

// ---------------- K5: QKV projection (MFMA). z==2 writes V pre-transposed ----
__global__ __launch_bounds__(256) void k_qkv_mfma(
    const u16* __restrict__ x16,
    const u16* __restrict__ WqT, const u16* __restrict__ WkT, const u16* __restrict__ WvT,
    const float* __restrict__ bq, const float* __restrict__ bk, const float* __restrict__ bv,
    u16* __restrict__ q, u16* __restrict__ k, u16* __restrict__ vt,
    const int* __restrict__ rmap, int G, int h0)
{
    int z = blockIdx.z;
    const u16* BT     = (z == 0) ? WqT : ((z == 1) ? WkT : WvT);
    const float* bias = (z == 0) ? bq  : ((z == 1) ? bk  : bv);
    int S = G << 8;
    int m0 = blockIdx.x * 128, n0 = blockIdx.y * 128;
    f4v acc[4][4];
    gemm_core(x16, DD, BT + (size_t)(h0 << 8) * DD, DD, 0, DD, NR, m0, n0, acc);
    bias += (h0 << 8);
    int t = threadIdx.x;
    int l = t & 63, w = t >> 6;
    int lg = l >> 4, li = l & 15;
    int wm = (w >> 1) * 64, wn = (w & 1) * 64;
    if (z < 2) {
        u16* out = (z == 0) ? q : k;
#pragma unroll
        for (int mt = 0; mt < 4; ++mt)
#pragma unroll
            for (int reg = 0; reg < 4; ++reg) {
                int row = m0 + wm + mt * 16 + lg * 4 + reg;
                if (row >= NR) continue;
#pragma unroll
                for (int nt = 0; nt < 4; ++nt) {
                    int col = n0 + wn + nt * 16 + li;
                    out[(size_t)row * S + col] = f2bf(acc[mt][nt][reg] + bias[col]);
                }
            }
    } else {   // V transposed: vt[col][b*512 + m], via LDS bounce
        __shared__ u16 tp[32][132];
        int mloc = t & 127;
        int row  = m0 + mloc;
        int rm_  = (row < NTOT) ? rmap[row] : -1;
        for (int c = 0; c < 4; ++c) {
            __syncthreads();
            if ((w & 1) == (c >> 1)) {
#pragma unroll
                for (int nt2 = 0; nt2 < 2; ++nt2) {
                    int nt = (c & 1) * 2 + nt2;
                    float bcol = bias[n0 + c * 32 + nt2 * 16 + li];
#pragma unroll
                    for (int mt = 0; mt < 4; ++mt)
#pragma unroll
                        for (int reg = 0; reg < 4; ++reg)
                            tp[nt2 * 16 + li][wm + mt * 16 + lg * 4 + reg] =
                                f2bf(acc[mt][nt][reg] + bcol);
                }
            }
            __syncthreads();
            if (rm_ >= 0) {
#pragma unroll
                for (int rr = 0; rr < 16; ++rr) {
                    int coll = rr * 2 + (t >> 7);
                    vt[(size_t)(n0 + c * 32 + coll) * NK + rm_] = tp[coll][mloc];
                }
            }
        }
    }
}

// ---------------- K6: MFMA flash attention (R11 + ones-MFMA denominator) -----
// Cooperative LDS staging + XCD swizzle, 128-VGPR target. Delta vs R11: the
// per-tile 16-shuffle l_run reduce is replaced by a 17th PV MFMA with an
// all-ones B fragment: lsum = mfma(P, ones, lsum) -> C[row][*] = row-sum of P,
// replicated across column lanes (exactly the normalization layout; no reduce
// anywhere). Same bf16 p values summed -> num/denom consistency preserved;
// only f32 association changes. ones frag is a transient LDS broadcast read.
__global__ __launch_bounds__(256) void k_attn_mfma(
    const u16* __restrict__ q, const u16* __restrict__ kb, const u16* __restrict__ vt,
    u16* __restrict__ o, const int* __restrict__ starts,
    const float* __restrict__ bv, int G, int h0)
{
    int wg = blockIdx.x;
    int rest = wg >> 3;
    int bh = (wg & 7) + 8 * (rest / QT);
    int qt = rest % QT;
    int b = bh / G, h = bh % G;
    int S = G << 8;
    int t = threadIdx.x, l = t & 63, w = t >> 6;
    int lg = l >> 4, li = l & 15;
    int start = starts[b];
    int N = starts[b + 1] - start; if (N > MAXN) N = MAXN;
    int R = N + 1;
    if (qt * 64 >= R) return;
    size_t hoff = (size_t)h << 8;

    if (N == 0) {   // all rows pad: softmax uniform over identical rows -> o = bv
        if (qt == 0) o[(size_t)(NTOT + b) * S + hoff + t] = f2bf(bv[((h0 + h) << 8) + t]);
        return;
    }

    __shared__ u16 k_lds[32 * KST];
    __shared__ u16 v_lds[256 * VST];
    __shared__ u16 p_lds[4][16 * VST];
    __shared__ u16 ones_lds[40];   // 32 bf16 ones (+pad)

    if (t < 16) reinterpret_cast<u32*>(ones_lds)[t] = 0x3F803F80u;  // synced by first barrier

    // Q fragments for this wave's 16 rows
    int qbase = qt * 64 + w * 16;
    int qiA = qbase + li; if (qiA > R - 1) qiA = R - 1;
    int growA = (qiA < N) ? (start + qiA) : (NTOT + b);
    const u16* qp = q + (size_t)growA * S + hoff;
    s8v qf[8];
#pragma unroll
    for (int ks = 0; ks < 8; ++ks)
        qf[ks] = *reinterpret_cast<const s8v*>(&qp[ks * 32 + lg * 8]);

    const f4v z4 = {0.f, 0.f, 0.f, 0.f};
    f4v O[16];
#pragma unroll
    for (int nt = 0; nt < 16; ++nt) O[nt] = z4;
    f4v lsum = z4;   // per-row softmax denominator, MFMA-accumulated (replicated per li)
    float m_run[4] = {-1e30f, -1e30f, -1e30f, -1e30f};

    const u16* vbh = vt + hoff * NK + (b << 9);
    int krow = t >> 3, kf0 = (t & 7) * 32;
    int nkt = (N + 31) >> 5;

    for (int kt = 0; kt < nkt; ++kt) {
        __syncthreads();   // all waves done reading previous LDS tile
        {   // stage K tile: 32 keys x 256 feats
            int ml = kt * 32 + krow; if (ml >= N) ml = N - 1;   // clamped rows masked later
            const u16* kp = kb + (size_t)(start + ml) * S + hoff + kf0;
#pragma unroll
            for (int it = 0; it < 4; ++it)
                *reinterpret_cast<s8v*>(&k_lds[krow * KST + kf0 + it * 8]) =
                    *reinterpret_cast<const s8v*>(&kp[it * 8]);
        }
        {   // stage V^T tile: 256 feats x 32 keys (global vt pre-transposed)
            const u16* vp = vbh + (size_t)t * NK + kt * 32;
#pragma unroll
            for (int it = 0; it < 4; ++it)
                *reinterpret_cast<s8v*>(&v_lds[t * VST + it * 8]) =
                    *reinterpret_cast<const s8v*>(&vp[it * 8]);
        }
        __syncthreads();

        // QK^T: C[q=row][key=col], two 16-key subtiles
        f4v s0 = z4, s1 = z4;
        __builtin_amdgcn_s_setprio(1);
#pragma unroll
        for (int ks = 0; ks < 8; ++ks) {
            s8v kf_0 = *reinterpret_cast<const s8v*>(&k_lds[li * KST + ks * 32 + lg * 8]);
            s8v kf_1 = *reinterpret_cast<const s8v*>(&k_lds[(16 + li) * KST + ks * 32 + lg * 8]);
            s0 = __builtin_amdgcn_mfma_f32_16x16x32_bf16(qf[ks], kf_0, s0, 0, 0, 0);
            s1 = __builtin_amdgcn_mfma_f32_16x16x32_bf16(qf[ks], kf_1, s1, 0, 0, 0);
        }
        __builtin_amdgcn_s_setprio(0);

        int key0 = kt * 32 + li, key1 = key0 + 16;
        float sm0[4], sm1[4];
        bool nb = false;
#pragma unroll
        for (int r = 0; r < 4; ++r) {
            sm0[r] = (key0 < N) ? s0[r] * 0.0625f : -1e30f;
            sm1[r] = (key1 < N) ? s1[r] * 0.0625f : -1e30f;
            nb = nb || (fmaxf(sm0[r], sm1[r]) > m_run[r] + THR);   // per-lane trigger
        }
        if (__any(nb)) {   // SLOW PATH (rare: ~tile 0 only) — full reduce + rescale
#pragma unroll
            for (int r = 0; r < 4; ++r) {
                float v2 = fmaxf(sm0[r], sm1[r]);
#pragma unroll
                for (int off = 8; off >= 1; off >>= 1) v2 = fmaxf(v2, __shfl_xor(v2, off, 64));
                float mn = fmaxf(m_run[r], v2);
                float sc = __expf(m_run[r] - mn);
                m_run[r] = mn; lsum[r] *= sc;
#pragma unroll
                for (int nt = 0; nt < 16; ++nt) O[nt][r] *= sc;
            }
        }
#pragma unroll
        for (int r = 0; r < 4; ++r) {
            p_lds[w][(lg * 4 + r) * VST + li]      = f2bf(__expf(sm0[r] - m_run[r]));
            p_lds[w][(lg * 4 + r) * VST + 16 + li] = f2bf(__expf(sm1[r] - m_run[r]));
        }

        // PV: A = P (rows=q, k=keys), B = V^T rows; 17th MFMA with ones-B
        // accumulates the per-row denominator (replicated across li lanes).
        s8v pa = *reinterpret_cast<const s8v*>(&p_lds[w][li * VST + lg * 8]);
        __builtin_amdgcn_s_setprio(1);
#pragma unroll
        for (int nt = 0; nt < 16; ++nt) {
            s8v vf = *reinterpret_cast<const s8v*>(&v_lds[(nt * 16 + li) * VST + lg * 8]);
            O[nt] = __builtin_amdgcn_mfma_f32_16x16x32_bf16(pa, vf, O[nt], 0, 0, 0);
        }
        {
            s8v of = *reinterpret_cast<const s8v*>(&ones_lds[lg * 8]);
            lsum = __builtin_amdgcn_mfma_f32_16x16x32_bf16(pa, of, lsum, 0, 0, 0);
        }
        __builtin_amdgcn_s_setprio(0);
    }

    // epilogue: normalize and store (lsum already replicated per column lane)
#pragma unroll
    for (int r = 0; r < 4; ++r) {
        int qi = qbase + lg * 4 + r;
        if (qi >= R) continue;
        int grow = (qi < N) ? (start + qi) : (NTOT + b);
        float inv = 1.f / lsum[r];
        u16* op = o + (size_t)grow * S + hoff;
#pragma unroll
        for (int nt = 0; nt < 16; ++nt)
            op[nt * 16 + li] = f2bf(O[nt][r] * inv);
    }
}

// ---------------- K7: acc += o @ Wo (MFMA, K-slice = this head group) --------
__global__ __launch_bounds__(256) void k_proj_mfma(
    const u16* __restrict__ o, const u16* __restrict__ WoT,
    float* __restrict__ acc, int G, int h0)
{
    int S = G << 8;
    int m0 = blockIdx.x * 128, n0 = blockIdx.y * 128;
    f4v av[4][4];
    gemm_core(o, S, WoT, HK, h0 << 8, S, NR, m0, n0, av);
    int l = threadIdx.x & 63, w = threadIdx.x >> 6;
    int wm = (w >> 1) * 64, wn = (w & 1) * 64;
#pragma unroll
    for (int mt = 0; mt < 4; ++mt)
#pragma unroll
        for (int reg = 0; reg < 4; ++reg) {
            int row = m0 + wm + mt * 16 + (l >> 4) * 4 + reg;
            if (row >= NR) continue;
#pragma unroll
            for (int nt = 0; nt < 4; ++nt) {
                int col = n0 + wn + nt * 16 + (l & 15);
                acc[(size_t)row * DD + col] += av[mt][nt][reg];   // one owner/elem
            }
        }
}

// ---------------- K8: LayerNorm (optionally also emit bf16 copy) -------------
__global__ __launch_bounds__(256) void k_ln(
    const float* __restrict__ in, const float* __restrict__ g, const float* __restrict__ be,
    float* __restrict__ outf, u16* __restrict__ out16)
{
    int w = threadIdx.x >> 6, lane = threadIdx.x & 63;
    int row = blockIdx.x * 4 + w;
    const float* a = &in[(size_t)row * DD];
    float v0 = a[lane], v1 = a[lane + 64], v2 = a[lane + 128], v3 = a[lane + 192];
    float s  = v0 + v1 + v2 + v3;
    float ss = v0 * v0 + v1 * v1 + v2 * v2 + v3 * v3;
#pragma unroll
    for (int off = 32; off > 0; off >>= 1) { s += __shfl_xor(s, off, 64); ss += __shfl_xor(ss, off, 64); }
    float mean = s * (1.f / 256.f);
    float var  = ss * (1.f / 256.f) - mean * mean;
    float rstd = rsqrtf(var + EPS);
    float r0 = (v0 - mean) * rstd * g[lane]       + be[lane];
    float r1 = (v1 - mean) * rstd * g[lane + 64]  + be[lane + 64];
    float r2 = (v2 - mean) * rstd * g[lane + 128] + be[lane + 128];
    float r3 = (v3 - mean) * rstd * g[lane + 192] + be[lane + 192];
    float* of = &outf[(size_t)row * DD];
    of[lane] = r0; of[lane + 64] = r1; of[lane + 128] = r2; of[lane + 192] = r3;
    if (out16) {
        u16* o6 = &out16[(size_t)row * DD];
        o6[lane] = f2bf(r0); o6[lane + 64] = f2bf(r1);
        o6[lane + 128] = f2bf(r2); o6[lane + 192] = f2bf(r3);
    }
}

// ---------------- K9: FFN1 (MFMA): ff16 = relu(h16 @ W1 + b1) ----------------
__global__ __launch_bounds__(256) void k_ffn1_mfma(
    const u16* __restrict__ h16, const u16* __restrict__ W1T, const float* __restrict__ b1,
    u16* __restrict__ ff16)
{
    int m0 = blockIdx.x * 128, n0 = blockIdx.y * 128;
    f4v acc[4][4];
    gemm_core(h16, DD, W1T, DD, 0, DD, NR, m0, n0, acc);
    int l = threadIdx.x & 63, w = threadIdx.x >> 6;
    int wm = (w >> 1) * 64, wn = (w & 1) * 64;
#pragma unroll
    for (int mt = 0; mt < 4; ++mt)
#pragma unroll
        for (int reg = 0; reg < 4; ++reg) {
            int row = m0 + wm + mt * 16 + (l >> 4) * 4 + reg;
            if (row >= NR) continue;
#pragma unroll
            for (int nt = 0; nt < 4; ++nt) {
                int col = n0 + wn + nt * 16 + (l & 15);
                ff16[(size_t)row * FF + col] = f2bf(fmaxf(acc[mt][nt][reg] + b1[col], 0.f));
            }
        }
}

// ---------------- K10: FFN2 (MFMA): out = ff16 @ W2 + b2 + h (residual) ------
__global__ __launch_bounds__(256) void k_ffn2_mfma(
    const u16* __restrict__ ff16, const u16* __restrict__ W2T, const float* __restrict__ b2,
    const float* __restrict__ hbuf, float* __restrict__ outf)
{
    int m0 = blockIdx.x * 128, n0 = blockIdx.y * 128;
    f4v acc[4][4];
    gemm_core(ff16, FF, W2T, FF, 0, FF, NR, m0, n0, acc);
    int l = threadIdx.x & 63, w = threadIdx.x >> 6;
    int wm = (w >> 1) * 64, wn = (w & 1) * 64;
#pragma unroll
    for (int mt = 0; mt < 4; ++mt)
#pragma unroll
        for (int reg = 0; reg < 4; ++reg) {
            int row = m0 + wm + mt * 16 + (l >> 4) * 4 + reg;
            if (row >= NR) continue;
#pragma unroll
            for (int nt = 0; nt < 4; ++nt) {
                int col = n0 + wn + nt * 16 + (l & 15);
                outf[(size_t)row * DD + col] = acc[mt][nt][reg] + b2[col] + hbuf[(size_t)row * DD + col];
            }
        }
}

// ---------------- K11: pooled readout (parallel 2-stage, fixed order) --------
__global__ __launch_bounds__(256) void k_pool1(
    const float* __restrict__ rowout, const int* __restrict__ starts, float* __restrict__ pws)
{
    int b = blockIdx.x, seg = blockIdx.y, d = threadIdx.x;
    int start = starts[b];
    int N = starts[b + 1] - start; if (N > MAXN) N = MAXN;
    int n0 = seg * 64, n1 = n0 + 64; if (n1 > N) n1 = N;
    float s = 0.f;
    for (int n = n0; n < n1; ++n) s += rowout[(size_t)(start + n) * DD + d];
    pws[((size_t)b * 8 + seg) * DD + d] = s;
}
__global__ void k_pool2(const float* __restrict__ pws, const float* __restrict__ rowout,
                        const int* __restrict__ starts, float* __restrict__ out)
{
    int b = blockIdx.x, d = threadIdx.x;
    int start = starts[b];
    int N = starts[b + 1] - start; if (N > MAXN) N = MAXN;
    float s = 0.f;
#pragma unroll
    for (int sg = 0; sg < 8; ++sg) s += pws[((size_t)b * 8 + sg) * DD + d];
    s += (float)(MAXN - N) * rowout[(size_t)(NTOT + b) * DD + d];
    out[(size_t)b * DD + d] = s * (1.f / 512.f);
}

extern "C" void kernel_launch(void* const* d_in, const int* in_sizes, int n_in,
                              void* d_out, int out_size, void* d_ws, size_t ws_size,
                              hipStream_t stream) {
    const float* x   = (const float*)d_in[0];
    const int*   ind = (const int*)d_in[1];
    const float* Wq  = (const float*)d_in[2];
    const float* Wk  = (const float*)d_in[3];
    const float* Wv  = (const float*)d_in[4];
    const float* Wo  = (const float*)d_in[5];
    const float* bq  = (const float*)d_in[6];
    const float* bk  = (const float*)d_in[7];
    const float* bv  = (const float*)d_in[8];
    const float* bo  = (const float*)d_in[9];
    const float* g1  = (const float*)d_in[10];
    const float* be1 = (const float*)d_in[11];
    const float* W1  = (const float*)d_in[12];
    const float* b1  = (const float*)d_in[13];
    const float* W2  = (const float*)d_in[14];
    const float* b2  = (const float*)d_in[15];
    const float* g2  = (const float*)d_in[16];
    const float* be2 = (const float*)d_in[17];
    float* out = (float*)d_out;
    (void)in_sizes; (void)n_in; (void)out_size;

    char* ws = (char*)d_ws;
    const size_t rb2  = (size_t)NR * DD * sizeof(u16);    // 13.1 MB
    const size_t rb4  = (size_t)NR * DD * sizeof(float);  // 26.3 MB
    const size_t ffb  = (size_t)NR * FF * sizeof(u16);    // 52.5 MB
    const size_t vtb1 = (size_t)DD * NK * sizeof(u16);    // per-head vt: 16.8 MB
    const size_t wq_b = (size_t)HK * DD * sizeof(u16);
    const size_t w1_b = (size_t)FF * DD * sizeof(u16);
    const size_t rmb  = (size_t)NTOT * sizeof(int);
    const size_t fixed = 512 + rmb + 2 * rb4 + 2 * rb2 + 4 * wq_b + 2 * w1_b;
    const size_t per_g = 2 * rb2 + vtb1;                  // q + k + vt per head

    int G = 8;   // largest head-group whose footprint fits
    for (;;) {
        size_t need = fixed + (size_t)G * per_g + ((2 * (size_t)G * rb2 >= ffb) ? 0 : ffb);
        if (need <= ws_size || G == 1) break;
        G >>= 1;
    }

    size_t off = 0;
    int* starts = (int*)ws;              off += 512;
    int* rmap   = (int*)(ws + off);      off += rmb;
    u16* q   = (u16*)(ws + off);         off += (size_t)G * rb2;
    u16* k   = (u16*)(ws + off);         off += (size_t)G * rb2;
    u16* vt  = (u16*)(ws + off);         off += (size_t)G * vtb1;
    float* acc  = (float*)(ws + off);    off += rb4;
    float* hbuf = (float*)(ws + off);    off += rb4;
    u16* x16 = (u16*)(ws + off);         off += rb2;
    u16* h16 = (u16*)(ws + off);         off += rb2;
    u16* WqT = (u16*)(ws + off);         off += wq_b;
    u16* WkT = (u16*)(ws + off);         off += wq_b;
    u16* WvT = (u16*)(ws + off);         off += wq_b;
    u16* WoT = (u16*)(ws + off);         off += wq_b;
    u16* W1T = (u16*)(ws + off);         off += w1_b;
    u16* W2T = (u16*)(ws + off);         off += w1_b;
    u16* ff16 = (2 * (size_t)G * rb2 >= ffb) ? q : (u16*)(ws + off);  // alias q∪k after attn
    u16* o = q;              // alias: each attn wg reads only its own q rows first
    float* pws = hbuf;       // pool partials: hbuf dead by pool time

    hipLaunchKernelGGL(k_starts,    dim3(1),    dim3(128), 0, stream, ind, starts);
    hipLaunchKernelGGL(k_rowmap,    dim3(100),  dim3(256), 0, stream, starts, rmap);
    hipLaunchKernelGGL(k_cast_init, dim3(NR),   dim3(256), 0, stream, x, bo, x16, acc);
    hipLaunchKernelGGL(k_prep_w,    dim3(2560), dim3(256), 0, stream,
                       Wq, Wk, Wv, Wo, W1, W2, WqT, WkT, WvT, WoT, W1T, W2T);
    for (int h0 = 0; h0 < HH; h0 += G) {
        hipLaunchKernelGGL(k_qkv_mfma,  dim3(MT, 2 * G, 3),  dim3(256), 0, stream,
                           x16, WqT, WkT, WvT, bq, bk, bv, q, k, vt, rmap, G, h0);
        hipLaunchKernelGGL(k_attn_mfma, dim3(BB * G * QT),   dim3(256), 0, stream,
                           q, k, vt, o, starts, bv, G, h0);
        hipLaunchKernelGGL(k_proj_mfma, dim3(MT, 2),         dim3(256), 0, stream,
                           o, WoT, acc, G, h0);
    }
    hipLaunchKernelGGL(k_ln,        dim3(NR / 4), dim3(256), 0, stream, acc, g1, be1, hbuf, h16);
    hipLaunchKernelGGL(k_ffn1_mfma, dim3(MT, 8),  dim3(256), 0, stream, h16, W1T, b1, ff16);
    hipLaunchKernelGGL(k_ffn2_mfma, dim3(MT, 2),  dim3(256), 0, stream, ff16, W2T, b2, hbuf, acc);
    hipLaunchKernelGGL(k_ln,        dim3(NR / 4), dim3(256), 0, stream, acc, g2, be2, acc, (u16*)nullptr);
    hipLaunchKernelGGL(k_pool1,     dim3(BB, 8),  dim3(256), 0, stream, acc, starts, pws);
    hipLaunchKernelGGL(k_pool2,     dim3(BB),     dim3(256), 0, stream, pws, acc, starts, out);
}

// Round 13
// 706.874 us; speedup vs baseline: 1.1981x; 1.1981x over previous
//
#include <hip/hip_runtime.h>
#include <cstdint>
#include <cstddef>

#define NTOT 25600
#define BB 64
#define MAXN 512
#define DD 256
#define HH 8
#define FF 1024
#define HK 2048
#define NR (NTOT + BB)          // real rows + 1 pad-representative per batch
#define NK (BB * MAXN)          // 32768: vt column space (per-batch 512-aligned)
#define MT ((NR + 127) / 128)   // 201 M-tiles
#define QT 9                    // ceil((MAXN+1)/64) q-tiles
#define EPS 1e-3f
#define KST 260                 // k_lds row stride (2-way free)
#define VST 36                  // v_lds / p_lds row stride (reads conflict-free)
#define THR 8.0f                // defer-max rescale threshold (T13; zero-reg-cost)

typedef unsigned short u16;
typedef unsigned int   u32;
typedef __attribute__((ext_vector_type(8))) short s8v;   // 8 bf16 (4 VGPRs)
typedef __attribute__((ext_vector_type(4))) float f4v;   // MFMA accumulator

__device__ __forceinline__ float bf2f(u16 u) { return __uint_as_float(((u32)u) << 16); }
__device__ __forceinline__ u16 f2bf(float f) {
    u32 x = __float_as_uint(f);
    return (u16)((x + 0x7fffu + ((x >> 16) & 1u)) >> 16);  // RNE; inputs finite
}

// async global->LDS, 16B per lane. LDS dest must be wave-uniform base + lane*16.
typedef const __attribute__((address_space(1))) unsigned int gq_t;
typedef __attribute__((address_space(3))) unsigned int lq_t;
__device__ __forceinline__ void gld16(const void* g, void* l) {
    __builtin_amdgcn_global_load_lds((gq_t*)g, (lq_t*)(uintptr_t)l, 16, 0, 0);
}

// ---------------- K1: segment starts via binary search (indicator sorted) ----
__global__ void k_starts(const int* __restrict__ ind, int* __restrict__ starts) {
    int b = threadIdx.x;
    if (b > BB) return;
    int lo = 0, hi = NTOT;
    while (lo < hi) { int mid = (lo + hi) >> 1; if (ind[mid] < b) lo = mid + 1; else hi = mid; }
    starts[b] = lo;   // starts[64] == NTOT
}

// ---------------- K1b: row -> b*512 + local_pos map (-1 if beyond 512) -------
__global__ __launch_bounds__(256) void k_rowmap(const int* __restrict__ starts,
                                                int* __restrict__ rmap) {
    int row = blockIdx.x * 256 + threadIdx.x;
    if (row >= NTOT) return;
    int lo = 0, hi = BB - 1;
    while (lo < hi) { int mid = (lo + hi + 1) >> 1; if (starts[mid] <= row) lo = mid; else hi = mid - 1; }
    int m = row - starts[lo];
    rmap[row] = (m < MAXN) ? ((lo << 9) + m) : -1;
}

// ---------------- K2: x16 = bf16(x) (pad rows 0);  acc = x + bo --------------
__global__ __launch_bounds__(256) void k_cast_init(
    const float* __restrict__ x, const float* __restrict__ bo,
    u16* __restrict__ x16, float* __restrict__ acc) {
    int row = blockIdx.x, t = threadIdx.x;
    float v = (row < NTOT) ? x[(size_t)row * DD + t] : 0.f;
    x16[(size_t)row * DD + t] = f2bf(v);
    acc[(size_t)row * DD + t] = ((row < NTOT) ? v : 0.f) + bo[t];
}

// ---------------- K3: weight transposes via LDS 32x32 tile (coalesced) -------
__global__ __launch_bounds__(256) void k_prep_w(
    const float* __restrict__ Wq, const float* __restrict__ Wk, const float* __restrict__ Wv,
    const float* __restrict__ Wo, const float* __restrict__ W1, const float* __restrict__ W2,
    u16* __restrict__ WqT, u16* __restrict__ WkT, u16* __restrict__ WvT,
    u16* __restrict__ WoT, u16* __restrict__ W1T, u16* __restrict__ W2T)
{
    int bid = blockIdx.x;
    const float* W; u16* WT; int kd, nd;
    if (bid < 512)       { W = Wq; WT = WqT; kd = 256;  nd = 2048; }
    else if (bid < 1024) { W = Wk; WT = WkT; kd = 256;  nd = 2048; bid -= 512; }
    else if (bid < 1536) { W = Wv; WT = WvT; kd = 256;  nd = 2048; bid -= 1024; }
    else if (bid < 2048) { W = Wo; WT = WoT; kd = 2048; nd = 256;  bid -= 1536; }
    else if (bid < 2304) { W = W1; WT = W1T; kd = 256;  nd = 1024; bid -= 2048; }
    else                 { W = W2; WT = W2T; kd = 1024; nd = 256;  bid -= 2304; }
    int tn = nd >> 5;
    int k0 = (bid / tn) << 5, n0 = (bid % tn) << 5;
    __shared__ float tile[32][33];
    int t = threadIdx.x;
    int cr = t >> 5, cc = t & 31;
#pragma unroll
    for (int i = 0; i < 4; ++i)
        tile[cr + i * 8][cc] = W[(size_t)(k0 + cr + i * 8) * nd + n0 + cc];
    __syncthreads();
#pragma unroll
    for (int i = 0; i < 4; ++i)
        WT[(size_t)(n0 + cr + i * 8) * kd + k0 + cc] = f2bf(tile[cc][cr + i * 8]);
}

// ---------------- MFMA GEMM core: C[128x128]=A[128xkw]*BT^T, gload_lds stage -
__device__ __forceinline__ void gemm_core(
    const u16* __restrict__ A, int lda,
    const u16* __restrict__ BT, int ldb, int kbeg, int kw,
    int M, int m0, int n0, f4v acc[4][4])
{
    __shared__ u16 As[128 * 64];
    __shared__ u16 Bs[128 * 64];
    int t = threadIdx.x;
    int l = t & 63, w = t >> 6;
    int wm = (w >> 1) * 64, wn = (w & 1) * 64;
    const f4v z4 = {0.f, 0.f, 0.f, 0.f};
#pragma unroll
    for (int i = 0; i < 4; ++i)
#pragma unroll
        for (int j = 0; j < 4; ++j) acc[i][j] = z4;

    for (int k0 = 0; k0 < kw; k0 += 64) {
#pragma unroll
        for (int it = 0; it < 4; ++it) {
            int chunk = it * 256 + t;
            int r = chunk >> 3, c8 = (chunk & 7) * 8;
            int ga = m0 + r; ga = (ga < M) ? ga : (M - 1);   // clamp: no OOB fault
            gld16(&A[(size_t)ga * lda + k0 + c8], &As[chunk * 8]);
            gld16(&BT[(size_t)(n0 + r) * ldb + kbeg + k0 + c8], &Bs[chunk * 8]);
        }
        __syncthreads();   // barrier drains vmcnt -> LDS tiles complete
#pragma unroll
        for (int ks = 0; ks < 64; ks += 32) {
            s8v af[4], bf[4];
#pragma unroll
            for (int mt = 0; mt < 4; ++mt)
                af[mt] = *reinterpret_cast<const s8v*>(&As[(wm + mt * 16 + (l & 15)) * 64 + ks + (l >> 4) * 8]);
#pragma unroll
            for (int nt = 0; nt < 4; ++nt)
                bf[nt] = *reinterpret_cast<const s8v*>(&Bs[(wn + nt * 16 + (l & 15)) * 64 + ks + (l >> 4) * 8]);
#pragma unroll
            for (int mt = 0; mt < 4; ++mt)
#pragma unroll
                for (int nt = 0; nt < 4; ++nt)
                    acc[mt][nt] = __builtin_amdgcn_mfma_f32_16x16x32_bf16(af[mt], bf[nt], acc[mt][nt], 0, 0, 0);
        }
        __syncthreads();
    }
}

// ---------------- K5: QKV projection (MFMA). z==2 writes V pre-transposed ----
__global__ __launch_bounds__(256) void k_qkv_mfma(
    const u16* __restrict__ x16,
    const u16* __restrict__ WqT, const u16* __restrict__ WkT, const u16* __restrict__ WvT,
    const float* __restrict__ bq, const float* __restrict__ bk, const float* __restrict__ bv,
    u16* __restrict__ q, u16* __restrict__ k, u16* __restrict__ vt,
    const int* __restrict__ rmap, int G, int h0)
{
    int z = blockIdx.z;
    const u16* BT     = (z == 0) ? WqT : ((z == 1) ? WkT : WvT);
    const float* bias = (z == 0) ? bq  : ((z == 1) ? bk  : bv);
    int S = G << 8;
    int m0 = blockIdx.x * 128, n0 = blockIdx.y * 128;
    f4v acc[4][4];
    gemm_core(x16, DD, BT + (size_t)(h0 << 8) * DD, DD, 0, DD, NR, m0, n0, acc);
    bias += (h0 << 8);
    int t = threadIdx.x;
    int l = t & 63, w = t >> 6;
    int lg = l >> 4, li = l & 15;
    int wm = (w >> 1) * 64, wn = (w & 1) * 64;
    if (z < 2) {
        u16* out = (z == 0) ? q : k;
#pragma unroll
        for (int mt = 0; mt < 4; ++mt)
#pragma unroll
            for (int reg = 0; reg < 4; ++reg) {
                int row = m0 + wm + mt * 16 + lg * 4 + reg;
                if (row >= NR) continue;
#pragma unroll
                for (int nt = 0; nt < 4; ++nt) {
                    int col = n0 + wn + nt * 16 + li;
                    out[(size_t)row * S + col] = f2bf(acc[mt][nt][reg] + bias[col]);
                }
            }
    } else {   // V transposed: vt[col][b*512 + m], via LDS bounce
        __shared__ u16 tp[32][132];
        int mloc = t & 127;
        int row  = m0 + mloc;
        int rm_  = (row < NTOT) ? rmap[row] : -1;
        for (int c = 0; c < 4; ++c) {
            __syncthreads();
            if ((w & 1) == (c >> 1)) {
#pragma unroll
                for (int nt2 = 0; nt2 < 2; ++nt2) {
                    int nt = (c & 1) * 2 + nt2;
                    float bcol = bias[n0 + c * 32 + nt2 * 16 + li];
#pragma unroll
                    for (int mt = 0; mt < 4; ++mt)
#pragma unroll
                        for (int reg = 0; reg < 4; ++reg)
                            tp[nt2 * 16 + li][wm + mt * 16 + lg * 4 + reg] =
                                f2bf(acc[mt][nt][reg] + bcol);
                }
            }
            __syncthreads();
            if (rm_ >= 0) {
#pragma unroll
                for (int rr = 0; rr < 16; ++rr) {
                    int coll = rr * 2 + (t >> 7);
                    vt[(size_t)(n0 + c * 32 + coll) * NK + rm_] = tp[coll][mloc];
                }
            }
        }
    }
}

// ---------------- K6: MFMA flash attention (R11 exact — the verified optimum) -
// Cooperative LDS staging + XCD swizzle, 128 VGPR / 18.6% occupancy. Fast-path
// THR trigger (per-lane compare + __any; bit-identical branch decision); full
// 16-shuffle reduce + rescale only in the rare slow path; per-tile l_run
// shuffle reduce (register-neutral — R9/R12 showed any deferred variant costs
// +4 VGPR -> occupancy cliff -> net loss).
__global__ __launch_bounds__(256) void k_attn_mfma(
    const u16* __restrict__ q, const u16* __restrict__ kb, const u16* __restrict__ vt,
    u16* __restrict__ o, const int* __restrict__ starts,
    const float* __restrict__ bv, int G, int h0)
{
    int wg = blockIdx.x;
    int rest = wg >> 3;
    int bh = (wg & 7) + 8 * (rest / QT);
    int qt = rest % QT;
    int b = bh / G, h = bh % G;
    int S = G << 8;
    int t = threadIdx.x, l = t & 63, w = t >> 6;
    int lg = l >> 4, li = l & 15;
    int start = starts[b];
    int N = starts[b + 1] - start; if (N > MAXN) N = MAXN;
    int R = N + 1;
    if (qt * 64 >= R) return;
    size_t hoff = (size_t)h << 8;

    if (N == 0) {   // all rows pad: softmax uniform over identical rows -> o = bv
        if (qt == 0) o[(size_t)(NTOT + b) * S + hoff + t] = f2bf(bv[((h0 + h) << 8) + t]);
        return;
    }

    __shared__ u16 k_lds[32 * KST];
    __shared__ u16 v_lds[256 * VST];
    __shared__ u16 p_lds[4][16 * VST];

    // Q fragments for this wave's 16 rows
    int qbase = qt * 64 + w * 16;
    int qiA = qbase + li; if (qiA > R - 1) qiA = R - 1;
    int growA = (qiA < N) ? (start + qiA) : (NTOT + b);
    const u16* qp = q + (size_t)growA * S + hoff;
    s8v qf[8];
#pragma unroll
    for (int ks = 0; ks < 8; ++ks)
        qf[ks] = *reinterpret_cast<const s8v*>(&qp[ks * 32 + lg * 8]);

    const f4v z4 = {0.f, 0.f, 0.f, 0.f};
    f4v O[16];
#pragma unroll
    for (int nt = 0; nt < 16; ++nt) O[nt] = z4;
    float m_run[4] = {-1e30f, -1e30f, -1e30f, -1e30f};
    float l_run[4] = {0.f, 0.f, 0.f, 0.f};

    const u16* vbh = vt + hoff * NK + (b << 9);
    int krow = t >> 3, kf0 = (t & 7) * 32;
    int nkt = (N + 31) >> 5;

    for (int kt = 0; kt < nkt; ++kt) {
        __syncthreads();   // all waves done reading previous LDS tile
        {   // stage K tile: 32 keys x 256 feats
            int ml = kt * 32 + krow; if (ml >= N) ml = N - 1;   // clamped rows masked later
            const u16* kp = kb + (size_t)(start + ml) * S + hoff + kf0;
#pragma unroll
            for (int it = 0; it < 4; ++it)
                *reinterpret_cast<s8v*>(&k_lds[krow * KST + kf0 + it * 8]) =
                    *reinterpret_cast<const s8v*>(&kp[it * 8]);
        }
        {   // stage V^T tile: 256 feats x 32 keys (global vt pre-transposed)
            const u16* vp = vbh + (size_t)t * NK + kt * 32;
#pragma unroll
            for (int it = 0; it < 4; ++it)
                *reinterpret_cast<s8v*>(&v_lds[t * VST + it * 8]) =
                    *reinterpret_cast<const s8v*>(&vp[it * 8]);
        }
        __syncthreads();

        // QK^T: C[q=row][key=col], two 16-key subtiles
        f4v s0 = z4, s1 = z4;
        __builtin_amdgcn_s_setprio(1);
#pragma unroll
        for (int ks = 0; ks < 8; ++ks) {
            s8v kf_0 = *reinterpret_cast<const s8v*>(&k_lds[li * KST + ks * 32 + lg * 8]);
            s8v kf_1 = *reinterpret_cast<const s8v*>(&k_lds[(16 + li) * KST + ks * 32 + lg * 8]);
            s0 = __builtin_amdgcn_mfma_f32_16x16x32_bf16(qf[ks], kf_0, s0, 0, 0, 0);
            s1 = __builtin_amdgcn_mfma_f32_16x16x32_bf16(qf[ks], kf_1, s1, 0, 0, 0);
        }
        __builtin_amdgcn_s_setprio(0);

        int key0 = kt * 32 + li, key1 = key0 + 16;
        float sm0[4], sm1[4];
        bool nb = false;
#pragma unroll
        for (int r = 0; r < 4; ++r) {
            sm0[r] = (key0 < N) ? s0[r] * 0.0625f : -1e30f;
            sm1[r] = (key1 < N) ? s1[r] * 0.0625f : -1e30f;
            nb = nb || (fmaxf(sm0[r], sm1[r]) > m_run[r] + THR);   // per-lane trigger
        }
        if (__any(nb)) {   // SLOW PATH (rare: ~tile 0 only) — full reduce + rescale
#pragma unroll
            for (int r = 0; r < 4; ++r) {
                float v2 = fmaxf(sm0[r], sm1[r]);
#pragma unroll
                for (int off = 8; off >= 1; off >>= 1) v2 = fmaxf(v2, __shfl_xor(v2, off, 64));
                float mn = fmaxf(m_run[r], v2);
                float sc = __expf(m_run[r] - mn);
                m_run[r] = mn; l_run[r] *= sc;
#pragma unroll
                for (int nt = 0; nt < 16; ++nt) O[nt][r] *= sc;
            }
        }
#pragma unroll
        for (int r = 0; r < 4; ++r) {
            u16 b0 = f2bf(__expf(sm0[r] - m_run[r]));
            u16 b1 = f2bf(__expf(sm1[r] - m_run[r]));
            p_lds[w][(lg * 4 + r) * VST + li]      = b0;
            p_lds[w][(lg * 4 + r) * VST + 16 + li] = b1;
            float sdum = bf2f(b0) + bf2f(b1);   // rounded p: num/denom consistency
#pragma unroll
            for (int off = 8; off >= 1; off >>= 1) sdum += __shfl_xor(sdum, off, 64);
            l_run[r] += sdum;
        }

        // PV: A = P (rows=q, k=keys), B = V^T rows (cols=feat, k=keys)
        s8v pa = *reinterpret_cast<const s8v*>(&p_lds[w][li * VST + lg * 8]);
        __builtin_amdgcn_s_setprio(1);
#pragma unroll
        for (int nt = 0; nt < 16; ++nt) {
            s8v vf = *reinterpret_cast<const s8v*>(&v_lds[(nt * 16 + li) * VST + lg * 8]);
            O[nt] = __builtin_amdgcn_mfma_f32_16x16x32_bf16(pa, vf, O[nt], 0, 0, 0);
        }
        __builtin_amdgcn_s_setprio(0);
    }

    // epilogue: normalize and store
#pragma unroll
    for (int r = 0; r < 4; ++r) {
        int qi = qbase + lg * 4 + r;
        if (qi >= R) continue;
        int grow = (qi < N) ? (start + qi) : (NTOT + b);
        float inv = 1.f / l_run[r];
        u16* op = o + (size_t)grow * S + hoff;
#pragma unroll
        for (int nt = 0; nt < 16; ++nt)
            op[nt * 16 + li] = f2bf(O[nt][r] * inv);
    }
}

// ---------------- K7: acc += o @ Wo (MFMA, K-slice = this head group) --------
__global__ __launch_bounds__(256) void k_proj_mfma(
    const u16* __restrict__ o, const u16* __restrict__ WoT,
    float* __restrict__ acc, int G, int h0)
{
    int S = G << 8;
    int m0 = blockIdx.x * 128, n0 = blockIdx.y * 128;
    f4v av[4][4];
    gemm_core(o, S, WoT, HK, h0 << 8, S, NR, m0, n0, av);
    int l = threadIdx.x & 63, w = threadIdx.x >> 6;
    int wm = (w >> 1) * 64, wn = (w & 1) * 64;
#pragma unroll
    for (int mt = 0; mt < 4; ++mt)
#pragma unroll
        for (int reg = 0; reg < 4; ++reg) {
            int row = m0 + wm + mt * 16 + (l >> 4) * 4 + reg;
            if (row >= NR) continue;
#pragma unroll
            for (int nt = 0; nt < 4; ++nt) {
                int col = n0 + wn + nt * 16 + (l & 15);
                acc[(size_t)row * DD + col] += av[mt][nt][reg];   // one owner/elem
            }
        }
}

// ---------------- K8: LayerNorm (optionally also emit bf16 copy) -------------
__global__ __launch_bounds__(256) void k_ln(
    const float* __restrict__ in, const float* __restrict__ g, const float* __restrict__ be,
    float* __restrict__ outf, u16* __restrict__ out16)
{
    int w = threadIdx.x >> 6, lane = threadIdx.x & 63;
    int row = blockIdx.x * 4 + w;
    const float* a = &in[(size_t)row * DD];
    float v0 = a[lane], v1 = a[lane + 64], v2 = a[lane + 128], v3 = a[lane + 192];
    float s  = v0 + v1 + v2 + v3;
    float ss = v0 * v0 + v1 * v1 + v2 * v2 + v3 * v3;
#pragma unroll
    for (int off = 32; off > 0; off >>= 1) { s += __shfl_xor(s, off, 64); ss += __shfl_xor(ss, off, 64); }
    float mean = s * (1.f / 256.f);
    float var  = ss * (1.f / 256.f) - mean * mean;
    float rstd = rsqrtf(var + EPS);
    float r0 = (v0 - mean) * rstd * g[lane]       + be[lane];
    float r1 = (v1 - mean) * rstd * g[lane + 64]  + be[lane + 64];
    float r2 = (v2 - mean) * rstd * g[lane + 128] + be[lane + 128];
    float r3 = (v3 - mean) * rstd * g[lane + 192] + be[lane + 192];
    float* of = &outf[(size_t)row * DD];
    of[lane] = r0; of[lane + 64] = r1; of[lane + 128] = r2; of[lane + 192] = r3;
    if (out16) {
        u16* o6 = &out16[(size_t)row * DD];
        o6[lane] = f2bf(r0); o6[lane + 64] = f2bf(r1);
        o6[lane + 128] = f2bf(r2); o6[lane + 192] = f2bf(r3);
    }
}

// ---------------- K9: FFN1 (MFMA): ff16 = relu(h16 @ W1 + b1) ----------------
__global__ __launch_bounds__(256) void k_ffn1_mfma(
    const u16* __restrict__ h16, const u16* __restrict__ W1T, const float* __restrict__ b1,
    u16* __restrict__ ff16)
{
    int m0 = blockIdx.x * 128, n0 = blockIdx.y * 128;
    f4v acc[4][4];
    gemm_core(h16, DD, W1T, DD, 0, DD, NR, m0, n0, acc);
    int l = threadIdx.x & 63, w = threadIdx.x >> 6;
    int wm = (w >> 1) * 64, wn = (w & 1) * 64;
#pragma unroll
    for (int mt = 0; mt < 4; ++mt)
#pragma unroll
        for (int reg = 0; reg < 4; ++reg) {
            int row = m0 + wm + mt * 16 + (l >> 4) * 4 + reg;
            if (row >= NR) continue;
#pragma unroll
            for (int nt = 0; nt < 4; ++nt) {
                int col = n0 + wn + nt * 16 + (l & 15);
                ff16[(size_t)row * FF + col] = f2bf(fmaxf(acc[mt][nt][reg] + b1[col], 0.f));
            }
        }
}

// ---------------- K10: FFN2 (MFMA): out = ff16 @ W2 + b2 + h (residual) ------
__global__ __launch_bounds__(256) void k_ffn2_mfma(
    const u16* __restrict__ ff16, const u16* __restrict__ W2T, const float* __restrict__ b2,
    const float* __restrict__ hbuf, float* __restrict__ outf)
{
    int m0 = blockIdx.x * 128, n0 = blockIdx.y * 128;
    f4v acc[4][4];
    gemm_core(ff16, FF, W2T, FF, 0, FF, NR, m0, n0, acc);
    int l = threadIdx.x & 63, w = threadIdx.x >> 6;
    int wm = (w >> 1) * 64, wn = (w & 1) * 64;
#pragma unroll
    for (int mt = 0; mt < 4; ++mt)
#pragma unroll
        for (int reg = 0; reg < 4; ++reg) {
            int row = m0 + wm + mt * 16 + (l >> 4) * 4 + reg;
            if (row >= NR) continue;
#pragma unroll
            for (int nt = 0; nt < 4; ++nt) {
                int col = n0 + wn + nt * 16 + (l & 15);
                outf[(size_t)row * DD + col] = acc[mt][nt][reg] + b2[col] + hbuf[(size_t)row * DD + col];
            }
        }
}

// ---------------- K11: pooled readout (parallel 2-stage, fixed order) --------
__global__ __launch_bounds__(256) void k_pool1(
    const float* __restrict__ rowout, const int* __restrict__ starts, float* __restrict__ pws)
{
    int b = blockIdx.x, seg = blockIdx.y, d = threadIdx.x;
    int start = starts[b];
    int N = starts[b + 1] - start; if (N > MAXN) N = MAXN;
    int n0 = seg * 64, n1 = n0 + 64; if (n1 > N) n1 = N;
    float s = 0.f;
    for (int n = n0; n < n1; ++n) s += rowout[(size_t)(start + n) * DD + d];
    pws[((size_t)b * 8 + seg) * DD + d] = s;
}
__global__ void k_pool2(const float* __restrict__ pws, const float* __restrict__ rowout,
                        const int* __restrict__ starts, float* __restrict__ out)
{
    int b = blockIdx.x, d = threadIdx.x;
    int start = starts[b];
    int N = starts[b + 1] - start; if (N > MAXN) N = MAXN;
    float s = 0.f;
#pragma unroll
    for (int sg = 0; sg < 8; ++sg) s += pws[((size_t)b * 8 + sg) * DD + d];
    s += (float)(MAXN - N) * rowout[(size_t)(NTOT + b) * DD + d];
    out[(size_t)b * DD + d] = s * (1.f / 512.f);
}

extern "C" void kernel_launch(void* const* d_in, const int* in_sizes, int n_in,
                              void* d_out, int out_size, void* d_ws, size_t ws_size,
                              hipStream_t stream) {
    const float* x   = (const float*)d_in[0];
    const int*   ind = (const int*)d_in[1];
    const float* Wq  = (const float*)d_in[2];
    const float* Wk  = (const float*)d_in[3];
    const float* Wv  = (const float*)d_in[4];
    const float* Wo  = (const float*)d_in[5];
    const float* bq  = (const float*)d_in[6];
    const float* bk  = (const float*)d_in[7];
    const float* bv  = (const float*)d_in[8];
    const float* bo  = (const float*)d_in[9];
    const float* g1  = (const float*)d_in[10];
    const float* be1 = (const float*)d_in[11];
    const float* W1  = (const float*)d_in[12];
    const float* b1  = (const float*)d_in[13];
    const float* W2  = (const float*)d_in[14];
    const float* b2  = (const float*)d_in[15];
    const float* g2  = (const float*)d_in[16];
    const float* be2 = (const float*)d_in[17];
    float* out = (float*)d_out;
    (void)in_sizes; (void)n_in; (void)out_size;

    char* ws = (char*)d_ws;
    const size_t rb2  = (size_t)NR * DD * sizeof(u16);    // 13.1 MB
    const size_t rb4  = (size_t)NR * DD * sizeof(float);  // 26.3 MB
    const size_t ffb  = (size_t)NR * FF * sizeof(u16);    // 52.5 MB
    const size_t vtb1 = (size_t)DD * NK * sizeof(u16);    // per-head vt: 16.8 MB
    const size_t wq_b = (size_t)HK * DD * sizeof(u16);
    const size_t w1_b = (size_t)FF * DD * sizeof(u16);
    const size_t rmb  = (size_t)NTOT * sizeof(int);
    const size_t fixed = 512 + rmb + 2 * rb4 + 2 * rb2 + 4 * wq_b + 2 * w1_b;
    const size_t per_g = 2 * rb2 + vtb1;                  // q + k + vt per head

    int G = 8;   // largest head-group whose footprint fits
    for (;;) {
        size_t need = fixed + (size_t)G * per_g + ((2 * (size_t)G * rb2 >= ffb) ? 0 : ffb);
        if (need <= ws_size || G == 1) break;
        G >>= 1;
    }

    size_t off = 0;
    int* starts = (int*)ws;              off += 512;
    int* rmap   = (int*)(ws + off);      off += rmb;
    u16* q   = (u16*)(ws + off);         off += (size_t)G * rb2;
    u16* k   = (u16*)(ws + off);         off += (size_t)G * rb2;
    u16* vt  = (u16*)(ws + off);         off += (size_t)G * vtb1;
    float* acc  = (float*)(ws + off);    off += rb4;
    float* hbuf = (float*)(ws + off);    off += rb4;
    u16* x16 = (u16*)(ws + off);         off += rb2;
    u16* h16 = (u16*)(ws + off);         off += rb2;
    u16* WqT = (u16*)(ws + off);         off += wq_b;
    u16* WkT = (u16*)(ws + off);         off += wq_b;
    u16* WvT = (u16*)(ws + off);         off += wq_b;
    u16* WoT = (u16*)(ws + off);         off += wq_b;
    u16* W1T = (u16*)(ws + off);         off += w1_b;
    u16* W2T = (u16*)(ws + off);         off += w1_b;
    u16* ff16 = (2 * (size_t)G * rb2 >= ffb) ? q : (u16*)(ws + off);  // alias q∪k after attn
    u16* o = q;              // alias: each attn wg reads only its own q rows first
    float* pws = hbuf;       // pool partials: hbuf dead by pool time

    hipLaunchKernelGGL(k_starts,    dim3(1),    dim3(128), 0, stream, ind, starts);
    hipLaunchKernelGGL(k_rowmap,    dim3(100),  dim3(256), 0, stream, starts, rmap);
    hipLaunchKernelGGL(k_cast_init, dim3(NR),   dim3(256), 0, stream, x, bo, x16, acc);
    hipLaunchKernelGGL(k_prep_w,    dim3(2560), dim3(256), 0, stream,
                       Wq, Wk, Wv, Wo, W1, W2, WqT, WkT, WvT, WoT, W1T, W2T);
    for (int h0 = 0; h0 < HH; h0 += G) {
        hipLaunchKernelGGL(k_qkv_mfma,  dim3(MT, 2 * G, 3),  dim3(256), 0, stream,
                           x16, WqT, WkT, WvT, bq, bk, bv, q, k, vt, rmap, G, h0);
        hipLaunchKernelGGL(k_attn_mfma, dim3(BB * G * QT),   dim3(256), 0, stream,
                           q, k, vt, o, starts, bv, G, h0);
        hipLaunchKernelGGL(k_proj_mfma, dim3(MT, 2),         dim3(256), 0, stream,
                           o, WoT, acc, G, h0);
    }
    hipLaunchKernelGGL(k_ln,        dim3(NR / 4), dim3(256), 0, stream, acc, g1, be1, hbuf, h16);
    hipLaunchKernelGGL(k_ffn1_mfma, dim3(MT, 8),  dim3(256), 0, stream, h16, W1T, b1, ff16);
    hipLaunchKernelGGL(k_ffn2_mfma, dim3(MT, 2),  dim3(256), 0, stream, ff16, W2T, b2, hbuf, acc);
    hipLaunchKernelGGL(k_ln,        dim3(NR / 4), dim3(256), 0, stream, acc, g2, be2, acc, (u16*)nullptr);
    hipLaunchKernelGGL(k_pool1,     dim3(BB, 8),  dim3(256), 0, stream, acc, starts, pws);
    hipLaunchKernelGGL(k_pool2,     dim3(BB),     dim3(256), 0, stream, pws, acc, starts, out);
}